// Round 1
// baseline (25.062 us; speedup 1.0000x reference)
//
#include <hip/hip_runtime.h>
#include <math.h>

// QuantumPerceptron: 5 qubits (DIM=32), 4 layers, 9 time steps.
// Key structure: M = diag(D) + omega * X_(qubit4)  ->  16 independent 2x2
// blocks, exp(-i t M) closed-form per block. U(l,u) = tensor product of 5
// single-qubit gates e^{-igZ} e^{-ibX} e^{-iaZ}. One lane per amplitude,
// pair exchange via __shfl_xor (masks 1..16 stay within each 32-lane half).

struct C2 { float x, y; };

__device__ __forceinline__ C2 cmul(C2 a, C2 b) {
    return { a.x * b.x - a.y * b.y, a.x * b.y + a.y * b.x };
}
__device__ __forceinline__ C2 cadd(C2 a, C2 b) { return { a.x + b.x, a.y + b.y }; }

__device__ __forceinline__ C2 shfl_xor_c2(C2 v, int mask) {
    C2 r;
    r.x = __shfl_xor(v.x, mask, 64);
    r.y = __shfl_xor(v.y, mask, 64);
    return r;
}

__global__ __launch_bounds__(320)
void qp_kernel(const float* __restrict__ state,   // 16 f32
               const float* __restrict__ params,  // (3,4,2,5) = 120 f32
               const float* __restrict__ W,       // (2,9) f32
               const float* __restrict__ bias,    // (2,) f32
               float* __restrict__ out)           // (1,2) f32
{
    __shared__ float r_lds[9];

    const int tid    = threadIdx.x;
    const int lane32 = tid & 31;   // amplitude index j (bit4=qubit0 .. bit0=qubit4)
    const int tstep  = tid >> 5;   // 0..8 valid, 9 = idle tail of wave 4
    const float t    = 0.1f * (float)(tstep + 1);

    // psi = kron(state, [1,0]) : even amplitudes = state[j/2], odd = 0
    C2 amp;
    amp.x = (lane32 & 1) ? 0.f : state[lane32 >> 1];
    amp.y = 0.f;

    for (int l = 0; l < 4; ++l) {
        for (int u = 0; u < 2; ++u) {
            // ---- U(l,u): 5 single-qubit gates, qubit i acts on bit (4-i) ----
            #pragma unroll
            for (int i = 0; i < 5; ++i) {
                const int base = l * 10 + u * 5 + i;
                const float a = params[base];          // params[0,l,u,i]
                const float b = params[40 + base];     // params[1,l,u,i]
                const float g = params[80 + base];     // params[2,l,u,i]
                float spg, cpg, samg, camg, sb, cb;
                sincosf(a + g, &spg, &cpg);
                sincosf(a - g, &samg, &camg);
                sincosf(b,     &sb,  &cb);
                // G = e^{-igZ} e^{-ibX} e^{-iaZ}
                // G00 = cb e^{-i(a+g)}, G11 = cb e^{+i(a+g)}
                // G01 = -i sb e^{+i(a-g)}, G10 = -i sb e^{-i(a-g)}
                const C2 G00 = { cb * cpg, -cb * spg };
                const C2 G11 = { cb * cpg,  cb * spg };
                const C2 G01 = {  sb * samg, -sb * camg };
                const C2 G10 = { -sb * samg, -sb * camg };
                const int msk = 1 << (4 - i);
                const C2 part = shfl_xor_c2(amp, msk);
                const bool hi = (lane32 & msk) != 0;
                const C2 dg = hi ? G11 : G00;
                const C2 of = hi ? G10 : G01;
                amp = cadd(cmul(dg, amp), cmul(of, part));
            }
            if (u == 0) {
                // ---- H(t) = exp(-i t M) on pair (j, j^1) ----
                const int m  = __popc(lane32 >> 1);
                const int b0 = lane32 & 1;
                const float fm = (float)m;
                const float corr = 4.f * fm - 8.f;          // (-8 + 4m) when b0 set
                const float Dj = -2.f * fm + (b0 ? corr : 0.f);
                const float Dp = -2.f * fm + (b0 ? 0.f : corr);
                const float cc  = 0.5f * (Dj + Dp);         // = -4 always
                const float hds = 0.5f * (Dj - Dp);         // signed half-detuning
                const float w   = -20.f;                    // omega
                const float Om  = sqrtf(hds * hds + w * w);
                float sth, cth, sct, cct;
                sincosf(Om * t, &sth, &cth);
                sincosf(cc * t, &sct, &cct);
                const float k = sth / Om;
                const C2 dg = { cth, -k * hds };            // cos - i sin*(A_jj)/Om
                const C2 of = { 0.f, -k * w };              // -i sin*w/Om
                const C2 part = shfl_xor_c2(amp, 1);
                C2 tmp = cadd(cmul(dg, amp), cmul(of, part));
                const C2 ph = { cct, -sct };                // e^{-i c t}
                amp = cmul(ph, tmp);
            }
        }
    }

    // r[t] = sum_even |amp|^2 - sum_odd |amp|^2, reduce within 32-lane group
    const float p = amp.x * amp.x + amp.y * amp.y;
    float sp = (lane32 & 1) ? -p : p;
    #pragma unroll
    for (int msk = 16; msk >= 1; msk >>= 1)
        sp += __shfl_xor(sp, msk, 64);
    if (lane32 == 0 && tstep < 9) r_lds[tstep] = sp;
    __syncthreads();

    // out[o] = tanh(sum_t r[t] * W[o,t] + bias[o]), o = 0,1
    if (tid < 2) {
        float acc = bias[tid];
        #pragma unroll
        for (int q = 0; q < 9; ++q) acc += r_lds[q] * W[tid * 9 + q];
        out[tid] = tanhf(acc);
    }
}

extern "C" void kernel_launch(void* const* d_in, const int* in_sizes, int n_in,
                              void* d_out, int out_size, void* d_ws, size_t ws_size,
                              hipStream_t stream) {
    const float* state  = (const float*)d_in[0];
    const float* params = (const float*)d_in[1];
    const float* W      = (const float*)d_in[2];
    const float* bias   = (const float*)d_in[3];
    float* out = (float*)d_out;
    qp_kernel<<<1, 320, 0, stream>>>(state, params, W, bias, out);
}

// Round 2
// 11.716 us; speedup vs baseline: 2.1392x; 2.1392x over previous
//
#include <hip/hip_runtime.h>
#include <math.h>

// QuantumPerceptron: 5 qubits (DIM=32), 4 layers, 9 time steps.
// M = diag(D) + omega * X_(qubit4)  ->  16 independent 2x2 blocks,
// exp(-i t M) in closed form (hoisted out of the layer loop; layer-invariant).
// U(l,u) = tensor product of 5 single-qubit gates e^{-igZ} e^{-ibX} e^{-iaZ}.
// One lane per amplitude; pair exchange via DPP quad_perm (masks 1,2) or
// ds_swizzle (masks 4,8,16), all confined to 32-lane groups (= time steps).
// H (mask 1) is merged with U1's last gate (also mask 1): one hop instead of two.

struct C2 { float x, y; };
__device__ __forceinline__ C2 cmul(C2 a, C2 b){ return {a.x*b.x - a.y*b.y, a.x*b.y + a.y*b.x}; }
__device__ __forceinline__ C2 cadd(C2 a, C2 b){ return {a.x+b.x, a.y+b.y}; }

// Cross-lane XOR exchange. DPP for masks 1,2 (VALU latency); ds_swizzle else.
template<int MASK>
__device__ __forceinline__ float xl(float v){
    int i = __builtin_bit_cast(int, v), r;
    if constexpr (MASK == 1)      r = __builtin_amdgcn_mov_dpp(i, 0xB1, 0xF, 0xF, true); // quad_perm [1,0,3,2]
    else if constexpr (MASK == 2) r = __builtin_amdgcn_mov_dpp(i, 0x4E, 0xF, 0xF, true); // quad_perm [2,3,0,1]
    else                          r = __builtin_amdgcn_ds_swizzle(i, (MASK << 10) | 0x1F); // BitMode xor
    return __builtin_bit_cast(float, r);
}
template<int MASK>
__device__ __forceinline__ C2 xl2(C2 v){ return { xl<MASK>(v.x), xl<MASK>(v.y) }; }

template<int MASK>
__device__ __forceinline__ C2 pair_op(C2 amp, C2 dg, C2 of){
    C2 p = xl2<MASK>(amp);
    return cadd(cmul(dg, amp), cmul(of, p));
}

// G = e^{-igZ} e^{-ibX} e^{-iaZ}; row selected by `hi`.
// G00 = cb e^{-i(a+g)}, G11 = cb e^{+i(a+g)}
// G01 = -i sb e^{+i(a-g)}, G10 = -i sb e^{-i(a-g)}
__device__ __forceinline__ void gate_coeffs(float a, float b, float g, bool hi, C2& dg, C2& of){
    float spg, cpg, samg, camg, sb, cb;
    __sincosf(a + g, &spg, &cpg);
    __sincosf(a - g, &samg, &camg);
    __sincosf(b,     &sb,  &cb);
    dg = { cb * cpg, hi ?  cb * spg : -cb * spg };
    of = { hi ? -sb * samg : sb * samg, -sb * camg };
}

template<int I>
__device__ __forceinline__ void gate(const float* __restrict__ params, int base, int lane32, C2& amp){
    constexpr int MASK = 1 << (4 - I);
    const float a = params[base + I], b = params[40 + base + I], g = params[80 + base + I];
    C2 dg, of;
    gate_coeffs(a, b, g, (lane32 & MASK) != 0, dg, of);
    amp = pair_op<MASK>(amp, dg, of);
}

__global__ __launch_bounds__(320)
void qp_kernel(const float* __restrict__ state,   // 16 f32
               const float* __restrict__ params,  // (3,4,2,5) = 120 f32
               const float* __restrict__ W,       // (2,9) f32
               const float* __restrict__ bias,    // (2,) f32
               float* __restrict__ out)           // (1,2) f32
{
    __shared__ float r_lds[9];

    const int tid    = threadIdx.x;
    const int lane32 = tid & 31;   // amplitude index
    const int tstep  = tid >> 5;   // 0..8 valid, 9 = idle tail
    const float t    = 0.1f * (float)(tstep + 1);

    // psi = kron(state, [1,0])
    C2 amp = { (lane32 & 1) ? 0.f : state[lane32 >> 1], 0.f };

    // ---- H(t) 2x2 on pair (j, j^1), hoisted: layer-invariant ----
    const int  b0  = lane32 & 1;
    const float fm = (float)__popc(lane32 >> 1);
    const float hds = (b0 ? 1.f : -1.f) * (2.f * fm - 4.f);  // signed half-detuning
    const float Om  = sqrtf(hds * hds + 400.f);              // omega = -20
    float sth, cth; __sincosf(Om * t, &sth, &cth);
    const float k = sth / Om;
    float s4, c4;  __sincosf(4.f * t, &s4, &c4);
    const C2 ph = { c4, s4 };                                 // e^{-i c t}, c = -4
    const C2 hdg = cmul(ph, C2{ cth, -k * hds });
    const C2 hof = cmul(ph, C2{ 0.f, 20.f * k });             // -i k w, w=-20

    #pragma unroll
    for (int l = 0; l < 4; ++l) {
        const int bA = l * 10, bB = l * 10 + 5;
        gate<0>(params, bA, lane32, amp);
        gate<1>(params, bA, lane32, amp);
        gate<2>(params, bA, lane32, amp);
        gate<3>(params, bA, lane32, amp);
        {   // U1 gate 4 (mask 1) merged with H (mask 1): M = H * G
            const float a = params[bA + 4], b = params[40 + bA + 4], g = params[80 + bA + 4];
            C2 dg, of; gate_coeffs(a, b, g, b0 != 0, dg, of);
            const C2 ndg = cadd(cmul(hdg, dg), cmul(hof, C2{ -of.x,  of.y }));  // + hof * of(partner row)
            const C2 nof = cadd(cmul(hdg, of), cmul(hof, C2{  dg.x, -dg.y }));  // + hof * dg(partner row)
            amp = pair_op<1>(amp, ndg, nof);
        }
        gate<0>(params, bB, lane32, amp);
        gate<1>(params, bB, lane32, amp);
        gate<2>(params, bB, lane32, amp);
        gate<3>(params, bB, lane32, amp);
        gate<4>(params, bB, lane32, amp);
    }

    // r[t] = sum_even |amp|^2 - sum_odd |amp|^2 within each 32-lane group
    const float p = amp.x * amp.x + amp.y * amp.y;
    float sp = b0 ? -p : p;
    sp += xl<16>(sp);
    sp += xl<8>(sp);
    sp += xl<4>(sp);
    sp += xl<2>(sp);
    sp += xl<1>(sp);
    if (lane32 == 0 && tstep < 9) r_lds[tstep] = sp;
    __syncthreads();

    // out[o] = tanh(sum_t r[t] * W[o,t] + bias[o])
    if (tid < 2) {
        float acc = bias[tid];
        #pragma unroll
        for (int q = 0; q < 9; ++q) acc += r_lds[q] * W[tid * 9 + q];
        out[tid] = tanhf(acc);
    }
}

extern "C" void kernel_launch(void* const* d_in, const int* in_sizes, int n_in,
                              void* d_out, int out_size, void* d_ws, size_t ws_size,
                              hipStream_t stream) {
    const float* state  = (const float*)d_in[0];
    const float* params = (const float*)d_in[1];
    const float* W      = (const float*)d_in[2];
    const float* bias   = (const float*)d_in[3];
    float* out = (float*)d_out;
    qp_kernel<<<1, 320, 0, stream>>>(state, params, W, bias, out);
}